// Round 1
// baseline (476.258 us; speedup 1.0000x reference)
//
#include <hip/hip_runtime.h>

// SpikeLoss: loss = 0.5 * sum((outputs - psp(target))^2)
// psp: syn_t = syn_{t-1}*(1-1/tau) + x_t, emit syn_t/tau  (tau=5 -> decay=0.8, inv_tau=0.2)
// Shape [B=16, C=128, H=16, W=16, T=100], T contiguous. 524288 independent neurons.

#define T_STEPS 100
#define N_NEURONS (16 * 128 * 16 * 16)
#define BLOCK 256
#define GRID (N_NEURONS / BLOCK)  // 2048

__global__ __launch_bounds__(BLOCK) void spike_loss_partial(
    const float* __restrict__ outputs,
    const float* __restrict__ target,
    float* __restrict__ partial) {
  const int n = blockIdx.x * BLOCK + threadIdx.x;  // neuron id
  const float4* __restrict__ t4 =
      reinterpret_cast<const float4*>(target + (size_t)n * T_STEPS);
  const float4* __restrict__ o4 =
      reinterpret_cast<const float4*>(outputs + (size_t)n * T_STEPS);

  const float decay = 0.8f;
  const float inv_tau = 0.2f;

  float syn = 0.0f;
  float acc = 0.0f;

#pragma unroll
  for (int j = 0; j < T_STEPS / 4; ++j) {
    float4 x = t4[j];
    float4 o = o4[j];
    float d;
    syn = fmaf(syn, decay, x.x); d = fmaf(syn, -inv_tau, o.x); acc = fmaf(d, d, acc);
    syn = fmaf(syn, decay, x.y); d = fmaf(syn, -inv_tau, o.y); acc = fmaf(d, d, acc);
    syn = fmaf(syn, decay, x.z); d = fmaf(syn, -inv_tau, o.z); acc = fmaf(d, d, acc);
    syn = fmaf(syn, decay, x.w); d = fmaf(syn, -inv_tau, o.w); acc = fmaf(d, d, acc);
  }

  // wave64 shuffle reduction
#pragma unroll
  for (int off = 32; off > 0; off >>= 1) acc += __shfl_down(acc, off, 64);

  __shared__ float wsum[BLOCK / 64];
  const int lane = threadIdx.x & 63;
  const int wid = threadIdx.x >> 6;
  if (lane == 0) wsum[wid] = acc;
  __syncthreads();
  if (threadIdx.x == 0) {
    partial[blockIdx.x] = wsum[0] + wsum[1] + wsum[2] + wsum[3];
  }
}

// Deterministic final reduction over the 2048 per-block partials; applies 0.5.
__global__ __launch_bounds__(256) void spike_loss_final(
    const float* __restrict__ partial, float* __restrict__ out, int nparts) {
  float acc = 0.0f;
  for (int i = threadIdx.x; i < nparts; i += 256) acc += partial[i];
#pragma unroll
  for (int off = 32; off > 0; off >>= 1) acc += __shfl_down(acc, off, 64);
  __shared__ float wsum[4];
  const int lane = threadIdx.x & 63;
  const int wid = threadIdx.x >> 6;
  if (lane == 0) wsum[wid] = acc;
  __syncthreads();
  if (threadIdx.x == 0) out[0] = 0.5f * (wsum[0] + wsum[1] + wsum[2] + wsum[3]);
}

// Fallback path if d_ws is unusably small: atomics into d_out (zeroed via memset).
__global__ __launch_bounds__(BLOCK) void spike_loss_atomic(
    const float* __restrict__ outputs,
    const float* __restrict__ target,
    float* __restrict__ out) {
  const int n = blockIdx.x * BLOCK + threadIdx.x;
  const float4* __restrict__ t4 =
      reinterpret_cast<const float4*>(target + (size_t)n * T_STEPS);
  const float4* __restrict__ o4 =
      reinterpret_cast<const float4*>(outputs + (size_t)n * T_STEPS);
  const float decay = 0.8f, inv_tau = 0.2f;
  float syn = 0.0f, acc = 0.0f;
#pragma unroll
  for (int j = 0; j < T_STEPS / 4; ++j) {
    float4 x = t4[j];
    float4 o = o4[j];
    float d;
    syn = fmaf(syn, decay, x.x); d = fmaf(syn, -inv_tau, o.x); acc = fmaf(d, d, acc);
    syn = fmaf(syn, decay, x.y); d = fmaf(syn, -inv_tau, o.y); acc = fmaf(d, d, acc);
    syn = fmaf(syn, decay, x.z); d = fmaf(syn, -inv_tau, o.z); acc = fmaf(d, d, acc);
    syn = fmaf(syn, decay, x.w); d = fmaf(syn, -inv_tau, o.w); acc = fmaf(d, d, acc);
  }
#pragma unroll
  for (int off = 32; off > 0; off >>= 1) acc += __shfl_down(acc, off, 64);
  __shared__ float wsum[BLOCK / 64];
  const int lane = threadIdx.x & 63, wid = threadIdx.x >> 6;
  if (lane == 0) wsum[wid] = acc;
  __syncthreads();
  if (threadIdx.x == 0)
    atomicAdd(out, 0.5f * (wsum[0] + wsum[1] + wsum[2] + wsum[3]));
}

extern "C" void kernel_launch(void* const* d_in, const int* in_sizes, int n_in,
                              void* d_out, int out_size, void* d_ws, size_t ws_size,
                              hipStream_t stream) {
  const float* outputs = (const float*)d_in[0];
  const float* target = (const float*)d_in[1];
  float* out = (float*)d_out;

  if (ws_size >= GRID * sizeof(float)) {
    float* partial = (float*)d_ws;
    spike_loss_partial<<<GRID, BLOCK, 0, stream>>>(outputs, target, partial);
    spike_loss_final<<<1, 256, 0, stream>>>(partial, out, GRID);
  } else {
    hipMemsetAsync(out, 0, sizeof(float), stream);
    spike_loss_atomic<<<GRID, BLOCK, 0, stream>>>(outputs, target, out);
  }
}

// Round 2
// 414.561 us; speedup vs baseline: 1.1488x; 1.1488x over previous
//
#include <hip/hip_runtime.h>

// SpikeLoss: loss = 0.5 * sum((outputs - psp(target))^2)
// psp: syn_t = syn_{t-1}*0.8 + x_t, emit syn_t/5   (tau=5)
// Shape [B=16, C=128, H=16, W=16, T=100], T contiguous. 524288 neurons.
//
// R2: wave-parallel scan over time. Lane l<50 holds float2 {x_{2l}, x_{2l+1}}
// of ONE neuron -> loads are cross-lane contiguous (400 B/row per inst).
// First-order linear recurrence scanned with Kogge-Stone; decay powers are
// compile-time constants, only the data term shuffles.

#define T_STEPS 100
#define N_NEURONS (16 * 128 * 16 * 16)  // 524288
#define BLOCK 256
#define GRID_P 2048                      // 8192 waves, 64 neurons per wave
#define NEUR_PER_WAVE (N_NEURONS / (GRID_P * BLOCK / 64))  // 64

__device__ __forceinline__ float wave_scan_psp(float X, int lane) {
  // inclusive scan: X_l += a^(2d) * X_{l-d},  a = 0.8
  float y;
  y = __shfl_up(X, 1);  if (lane >= 1)  X = fmaf(y, 0.64f, X);
  y = __shfl_up(X, 2);  if (lane >= 2)  X = fmaf(y, 0.4096f, X);
  y = __shfl_up(X, 4);  if (lane >= 4)  X = fmaf(y, 0.16777216f, X);
  y = __shfl_up(X, 8);  if (lane >= 8)  X = fmaf(y, 2.81474977e-2f, X);
  y = __shfl_up(X, 16); if (lane >= 16) X = fmaf(y, 7.92281625e-4f, X);
  y = __shfl_up(X, 32); if (lane >= 32) X = fmaf(y, 6.27710174e-7f, X);
  return X;
}

__global__ __launch_bounds__(BLOCK) void spike_loss_partial(
    const float* __restrict__ outputs,
    const float* __restrict__ target,
    float* __restrict__ partial) {
  const int lane = threadIdx.x & 63;
  const int wave = (blockIdx.x * BLOCK + threadIdx.x) >> 6;  // 0..8191
  const bool active = lane < 50;  // 50 float2 = 100 timesteps

  float acc = 0.0f;
  size_t n0 = (size_t)wave * NEUR_PER_WAVE;

#pragma unroll 2
  for (int i = 0; i < NEUR_PER_WAVE; ++i) {
    const float* row_t = target + (n0 + i) * T_STEPS;
    const float* row_o = outputs + (n0 + i) * T_STEPS;
    float2 x = active ? reinterpret_cast<const float2*>(row_t)[lane]
                      : make_float2(0.f, 0.f);
    float2 o = active ? reinterpret_cast<const float2*>(row_o)[lane]
                      : make_float2(0.f, 0.f);

    float X = fmaf(x.x, 0.8f, x.y);     // pair prefix: a*x0 + x1
    X = wave_scan_psp(X, lane);         // X = syn at t = 2l+1
    float syn1 = X;
    float syn0 = (X - x.y) * 1.25f;     // syn at t = 2l  (1/0.8 exact)

    float d0 = fmaf(syn0, -0.2f, o.x);  // o - syn/tau
    float d1 = fmaf(syn1, -0.2f, o.y);
    if (active) acc = fmaf(d0, d0, fmaf(d1, d1, acc));
  }

  // wave64 reduction
#pragma unroll
  for (int off = 32; off > 0; off >>= 1) acc += __shfl_down(acc, off, 64);

  __shared__ float wsum[BLOCK / 64];
  const int wid = threadIdx.x >> 6;
  if (lane == 0) wsum[wid] = acc;
  __syncthreads();
  if (threadIdx.x == 0)
    partial[blockIdx.x] = wsum[0] + wsum[1] + wsum[2] + wsum[3];
}

// Deterministic final reduction over per-block partials; applies the 0.5.
__global__ __launch_bounds__(256) void spike_loss_final(
    const float* __restrict__ partial, float* __restrict__ out, int nparts) {
  float acc = 0.0f;
  for (int i = threadIdx.x; i < nparts; i += 256) acc += partial[i];
#pragma unroll
  for (int off = 32; off > 0; off >>= 1) acc += __shfl_down(acc, off, 64);
  __shared__ float wsum[4];
  const int lane = threadIdx.x & 63;
  const int wid = threadIdx.x >> 6;
  if (lane == 0) wsum[wid] = acc;
  __syncthreads();
  if (threadIdx.x == 0) out[0] = 0.5f * (wsum[0] + wsum[1] + wsum[2] + wsum[3]);
}

// Fallback if d_ws is unusably small: atomic finish (threshold is 3.4e4; fp
// atomic ordering noise is irrelevant).
__global__ __launch_bounds__(BLOCK) void spike_loss_atomic(
    const float* __restrict__ outputs,
    const float* __restrict__ target,
    float* __restrict__ out) {
  const int lane = threadIdx.x & 63;
  const int wave = (blockIdx.x * BLOCK + threadIdx.x) >> 6;
  const bool active = lane < 50;
  float acc = 0.0f;
  size_t n0 = (size_t)wave * NEUR_PER_WAVE;
#pragma unroll 2
  for (int i = 0; i < NEUR_PER_WAVE; ++i) {
    const float* row_t = target + (n0 + i) * T_STEPS;
    const float* row_o = outputs + (n0 + i) * T_STEPS;
    float2 x = active ? reinterpret_cast<const float2*>(row_t)[lane]
                      : make_float2(0.f, 0.f);
    float2 o = active ? reinterpret_cast<const float2*>(row_o)[lane]
                      : make_float2(0.f, 0.f);
    float X = fmaf(x.x, 0.8f, x.y);
    X = wave_scan_psp(X, lane);
    float syn1 = X;
    float syn0 = (X - x.y) * 1.25f;
    float d0 = fmaf(syn0, -0.2f, o.x);
    float d1 = fmaf(syn1, -0.2f, o.y);
    if (active) acc = fmaf(d0, d0, fmaf(d1, d1, acc));
  }
#pragma unroll
  for (int off = 32; off > 0; off >>= 1) acc += __shfl_down(acc, off, 64);
  __shared__ float wsum[BLOCK / 64];
  const int wid = threadIdx.x >> 6;
  if (lane == 0) wsum[wid] = acc;
  __syncthreads();
  if (threadIdx.x == 0)
    atomicAdd(out, 0.5f * (wsum[0] + wsum[1] + wsum[2] + wsum[3]));
}

extern "C" void kernel_launch(void* const* d_in, const int* in_sizes, int n_in,
                              void* d_out, int out_size, void* d_ws, size_t ws_size,
                              hipStream_t stream) {
  const float* outputs = (const float*)d_in[0];
  const float* target = (const float*)d_in[1];
  float* out = (float*)d_out;

  if (ws_size >= GRID_P * sizeof(float)) {
    float* partial = (float*)d_ws;
    spike_loss_partial<<<GRID_P, BLOCK, 0, stream>>>(outputs, target, partial);
    spike_loss_final<<<1, 256, 0, stream>>>(partial, out, GRID_P);
  } else {
    hipMemsetAsync(out, 0, sizeof(float), stream);
    spike_loss_atomic<<<GRID_P, BLOCK, 0, stream>>>(outputs, target, out);
  }
}